// Round 1
// 471.836 us; speedup vs baseline: 1.0182x; 1.0182x over previous
//
#include <hip/hip_runtime.h>
#include <hip/hip_bf16.h>

// Problem constants
#define NBATCH 32
#define NTIME  2048
#define NOBJ   18
#define KIN    1500
#define NH     512
#define NTOT   1536   // 2H + DOUT
#define NM     65536  // NBATCH*NTIME

typedef __attribute__((ext_vector_type(4))) float f32x4;
typedef __attribute__((ext_vector_type(8))) short s16x8;
typedef __attribute__((ext_vector_type(4))) short s16x4;

static __device__ __forceinline__ short f2bf(float f) {
  union { float f; unsigned u; } v; v.f = f;
  unsigned r = v.u + 0x7fffu + ((v.u >> 16) & 1u);
  return (short)(r >> 16);
}

static __device__ __forceinline__ void gload_lds16(const short* g, short* l) {
  __builtin_amdgcn_global_load_lds(
      (const __attribute__((address_space(1))) unsigned int*)(g),
      (__attribute__((address_space(3))) unsigned int*)(l), 16, 0, 0);
}

// Transpose+convert+pad src[K][Nsrc] f32 -> bf16 chunks [cb][kt][row256][kc64],
// with the LDS XOR swizzle baked into the global layout (kc ^ ((row&7)<<3)).
__global__ void k_prep(const float* __restrict__ src, short* __restrict__ dst,
                       int K, int Nsrc, int nkt, int total) {
  int i = blockIdx.x * 256 + threadIdx.x;
  if (i >= total) return;
  int chunk = i >> 14, off = i & 16383;
  int row = off >> 6, kcp = off & 63;
  int kc = kcp ^ ((row & 7) << 3);
  int cb = chunk / nkt, kt = chunk - cb * nkt;
  int n = cb * 256 + row, k = kt * 64 + kc;
  dst[i] = (k < K) ? f2bf(src[(size_t)k * Nsrc + n]) : (short)0;
}

// GEMM1: h = relu(trip @ w1a + b1a). 256x256 tile, BK=64, 4-phase K-tile
// schedule with counted vmcnt; A f32 reg-staged (issue phase0, LDS-write
// phase3); B bf16 half-tile DMA via global_load_lds. 8 waves (2Mx4N), each
// owning a 128x64 output split into 4 quadrants (one per phase).
__launch_bounds__(512, 2)
__global__ void k_gemm1(const float* __restrict__ A, const short* __restrict__ Bc,
                        const float* __restrict__ bias, short* __restrict__ Hc) {
  __shared__ short lA[2][256 * 64];   // 64 KB
  __shared__ short lB[2][256 * 64];   // 64 KB
  const int g = blockIdx.x;
  const int lid = (g & 7) * 64 + (g >> 3);   // 512 blocks, bijective XCD swizzle
  const int rb = lid >> 1, cb = lid & 1;     // cb fastest: A rows reused in-XCD
  const int m0 = rb * 256, n0 = cb * 256;
  const int tid = threadIdx.x;
  const int lane = tid & 63, w = tid >> 6;
  const int wr = w >> 2, wc = w & 3;
  const int rlane = lane & 15, ksel = (lane >> 4) * 8;
  const int swz = (rlane & 7) << 3;
  const int kx0 = ksel ^ swz, kx1 = (32 | ksel) ^ swz;
  const int arow = tid >> 4;          // 0..31
  const int akq  = (tid & 15) * 4;    // 0..60
  const short* bchunk = Bc + (size_t)(cb * 24) * 16384;

  f32x4 acc[8][4] = {};
  float4 av[8];
  s16x8 af[4][2];      // A frags of current row-half (rh)
  s16x8 bfr[2][2];     // B frags of current col-half (ch)

  auto issueA = [&](int kt) {
    const int kbase = kt * 64;
    const bool fullq = (kt < 23) | (akq <= 24);  // K=1500 tail
#pragma unroll
    for (int i = 0; i < 8; ++i) {
      const float* p = A + (size_t)(m0 + arow + i * 32) * KIN + kbase + akq;
      av[i] = fullq ? *(const float4*)p : make_float4(0.f, 0.f, 0.f, 0.f);
    }
  };
  auto writeA = [&](int nb) {
#pragma unroll
    for (int i = 0; i < 8; ++i) {
      int r = arow + i * 32;
      s16x4 h4;
      h4[0] = f2bf(av[i].x); h4[1] = f2bf(av[i].y);
      h4[2] = f2bf(av[i].z); h4[3] = f2bf(av[i].w);
      *(s16x4*)&lA[nb][r * 64 + (akq ^ ((r & 7) << 3))] = h4;
    }
  };
  auto issueB = [&](int nb, int kt, int h) {  // h = B half-tile (128 rows)
    const short* src = bchunk + (size_t)kt * 16384 + h * 8192 + tid * 8;
#pragma unroll
    for (int j = 0; j < 2; ++j)
      gload_lds16(src + j * 4096, &lB[nb][h * 8192 + tid * 8 + j * 4096]);
  };
  auto readA = [&](int cu, int rh) {
#pragma unroll
    for (int mm = 0; mm < 4; ++mm) {
      int ro = (rh * 128 + wr * 64 + mm * 16 + rlane) * 64;
      af[mm][0] = *(const s16x8*)&lA[cu][ro + kx0];
      af[mm][1] = *(const s16x8*)&lA[cu][ro + kx1];
    }
  };
  auto readB = [&](int cu, int ch) {
#pragma unroll
    for (int qn = 0; qn < 2; ++qn) {
      int ro = (ch * 128 + wc * 32 + qn * 16 + rlane) * 64;
      bfr[qn][0] = *(const s16x8*)&lB[cu][ro + kx0];
      bfr[qn][1] = *(const s16x8*)&lB[cu][ro + kx1];
    }
  };
  auto mfma_quad = [&](int rh, int ch) {
    __builtin_amdgcn_s_setprio(1);
#pragma unroll
    for (int j = 0; j < 2; ++j)
#pragma unroll
      for (int mm = 0; mm < 4; ++mm)
#pragma unroll
        for (int qn = 0; qn < 2; ++qn)
          acc[rh * 4 + mm][ch * 2 + qn] = __builtin_amdgcn_mfma_f32_16x16x32_bf16(
              af[mm][j], bfr[qn][j], acc[rh * 4 + mm][ch * 2 + qn], 0, 0, 0);
    __builtin_amdgcn_s_setprio(0);
  };

  // prologue: stage tile 0 (queue order: A regs (8), Bh0 (2), Bh1 (2))
  issueA(0);
  issueB(0, 0, 0);
  issueB(0, 0, 1);
  writeA(0);   // compiler inserts precise vmcnt wait for av
  asm volatile("s_waitcnt lgkmcnt(0)" ::: "memory");

  // Per-tile queue (issued during previous tile): [A'(8), Bh0'(2), Bh1'(2)].
  // Tile-entry invariant: outstanding <= {Bh0,Bh1} of this tile (A was drained
  // by the writeA wait last tile). Phases consume quadrants (rh,ch) in order
  // (0,0),(0,1),(1,1),(1,0); B halves needed at p0 / p1; A is LDS-resident.
#define G1_TILE(KT, W0S, W1S, HASNEXT)                                  \
  {                                                                     \
    const int cu = (KT) & 1, nb = cu ^ 1;                               \
    asm volatile("s_waitcnt vmcnt(" W0S ")" ::: "memory");              \
    __builtin_amdgcn_s_barrier();                                       \
    asm volatile("" ::: "memory");                                      \
    if (HASNEXT) issueA((KT) + 1);                                      \
    readA(cu, 0); readB(cu, 0);                                         \
    mfma_quad(0, 0);                                                    \
    asm volatile("s_waitcnt vmcnt(" W1S ")" ::: "memory");              \
    __builtin_amdgcn_s_barrier();                                       \
    asm volatile("" ::: "memory");                                      \
    if (HASNEXT) issueB(nb, (KT) + 1, 0);                               \
    readB(cu, 1);                                                       \
    mfma_quad(0, 1);                                                    \
    __builtin_amdgcn_s_barrier();                                       \
    asm volatile("" ::: "memory");                                      \
    if (HASNEXT) issueB(nb, (KT) + 1, 1);                               \
    readA(cu, 1);                                                       \
    mfma_quad(1, 1);                                                    \
    __builtin_amdgcn_s_barrier();                                       \
    asm volatile("" ::: "memory");                                      \
    if (HASNEXT) writeA(nb);                                            \
    readB(cu, 0);                                                       \
    mfma_quad(1, 0);                                                    \
    if (HASNEXT) asm volatile("s_waitcnt lgkmcnt(0)" ::: "memory");     \
  }

#pragma unroll 1
  for (int kt = 0; kt < 23; ++kt) G1_TILE(kt, "2", "8", 1);
  G1_TILE(23, "2", "0", 0);
#undef G1_TILE

  // epilogue: bias + relu, store as chunked-swizzled bf16 for GEMM2's A DMA
#pragma unroll
  for (int n = 0; n < 4; ++n) {
    int c = n0 + (n >> 1) * 128 + wc * 32 + (n & 1) * 16 + rlane;
    float bv = bias[c];
#pragma unroll
    for (int m = 0; m < 8; ++m) {
      int rbase = m0 + (m >> 2) * 128 + wr * 64 + (m & 3) * 16 + ((lane >> 4) << 2);
#pragma unroll
      for (int q = 0; q < 4; ++q) {
        int r = rbase + q;
        float v = acc[m][n][q] + bv;
        v = v > 0.f ? v : 0.f;
        Hc[(size_t)(((r >> 8) * 8 + (c >> 6)) * 16384) + (r & 255) * 64 +
           ((c & 63) ^ ((r & 7) << 3))] = f2bf(v);
      }
    }
  }
}

// GEMM2: new_t = relu(h @ w1b + b1b). 256x256 tile, both operands DMA'd from
// pre-swizzled chunks in half-tiles, same 4-phase counted-vmcnt schedule.
// Fused epilogue: p_vecs store, s/o masked atomic scatter into contrib.
__launch_bounds__(512, 2)
__global__ void k_gemm2(const short* __restrict__ Ac, const short* __restrict__ Bc,
                        const float* __restrict__ bias, const int* __restrict__ index,
                        const int* __restrict__ rel_lens,
                        float* __restrict__ contrib, float* __restrict__ out) {
  __shared__ short lA[2][256 * 64];
  __shared__ short lB[2][256 * 64];
  const int g = blockIdx.x;
  const int lid = (g & 7) * 192 + (g >> 3);   // 1536 blocks, bijective
  const int rb = lid / 6, cb = lid - rb * 6;
  const int m0 = rb * 256;
  const int tid = threadIdx.x;
  const int lane = tid & 63, w = tid >> 6;
  const int wr = w >> 2, wc = w & 3;
  const int rlane = lane & 15, ksel = (lane >> 4) * 8;
  const int swz = (rlane & 7) << 3;
  const int kx0 = ksel ^ swz, kx1 = (32 | ksel) ^ swz;
  const short* achunk = Ac + (size_t)(rb * 8) * 16384;
  const short* bchunk = Bc + (size_t)(cb * 8) * 16384;

  f32x4 acc[8][4] = {};
  s16x8 af[4][2], bf0[2][2], bf1[2][2];

  auto issueA = [&](int nb, int kt, int h) {
    const short* src = achunk + (size_t)kt * 16384 + h * 8192 + tid * 8;
#pragma unroll
    for (int j = 0; j < 2; ++j)
      gload_lds16(src + j * 4096, &lA[nb][h * 8192 + tid * 8 + j * 4096]);
  };
  auto issueB = [&](int nb, int kt, int h) {
    const short* src = bchunk + (size_t)kt * 16384 + h * 8192 + tid * 8;
#pragma unroll
    for (int j = 0; j < 2; ++j)
      gload_lds16(src + j * 4096, &lB[nb][h * 8192 + tid * 8 + j * 4096]);
  };
  auto readA = [&](int cu, int rh) {
#pragma unroll
    for (int mm = 0; mm < 4; ++mm) {
      int ro = (rh * 128 + wr * 64 + mm * 16 + rlane) * 64;
      af[mm][0] = *(const s16x8*)&lA[cu][ro + kx0];
      af[mm][1] = *(const s16x8*)&lA[cu][ro + kx1];
    }
  };
  auto readB = [&](int cu, int ch, s16x8 (&dst)[2][2]) {
#pragma unroll
    for (int qn = 0; qn < 2; ++qn) {
      int ro = (ch * 128 + wc * 32 + qn * 16 + rlane) * 64;
      dst[qn][0] = *(const s16x8*)&lB[cu][ro + kx0];
      dst[qn][1] = *(const s16x8*)&lB[cu][ro + kx1];
    }
  };
  auto mfma_quad = [&](int rh, int ch, s16x8 (&bfr)[2][2]) {
    __builtin_amdgcn_s_setprio(1);
#pragma unroll
    for (int j = 0; j < 2; ++j)
#pragma unroll
      for (int mm = 0; mm < 4; ++mm)
#pragma unroll
        for (int qn = 0; qn < 2; ++qn)
          acc[rh * 4 + mm][ch * 2 + qn] = __builtin_amdgcn_mfma_f32_16x16x32_bf16(
              af[mm][j], bfr[qn][j], acc[rh * 4 + mm][ch * 2 + qn], 0, 0, 0);
    __builtin_amdgcn_s_setprio(0);
  };

  // prologue: stage tile 0; queue order per tile = [Ah0, Bh0, Bh1, Ah1]
  issueA(0, 0, 0);
  issueB(0, 0, 0);
  issueB(0, 0, 1);
  issueA(0, 0, 1);

  // Phases (0,0),(0,1),(1,1),(1,0) need Ah0+Bh0 / Bh1 / Ah1 / nothing.
  // Steady waits all vmcnt(4): each leaves exactly the 2 younger groups of
  // this tile's remainder + the 2 just-issued next-tile groups in flight.
#define G2_TILE(KT, W0S, W1S, W2S, HASNEXT)                             \
  {                                                                     \
    const int cu = (KT) & 1, nb = cu ^ 1;                               \
    asm volatile("s_waitcnt vmcnt(" W0S ")" ::: "memory");              \
    __builtin_amdgcn_s_barrier();                                       \
    asm volatile("" ::: "memory");                                      \
    if (HASNEXT) issueA(nb, (KT) + 1, 0);                               \
    readA(cu, 0); readB(cu, 0, bf0);                                    \
    mfma_quad(0, 0, bf0);                                               \
    asm volatile("s_waitcnt vmcnt(" W1S ")" ::: "memory");              \
    __builtin_amdgcn_s_barrier();                                       \
    asm volatile("" ::: "memory");                                      \
    if (HASNEXT) issueB(nb, (KT) + 1, 0);                               \
    readB(cu, 1, bf1);                                                  \
    mfma_quad(0, 1, bf1);                                               \
    asm volatile("s_waitcnt vmcnt(" W2S ")" ::: "memory");              \
    __builtin_amdgcn_s_barrier();                                       \
    asm volatile("" ::: "memory");                                      \
    if (HASNEXT) issueB(nb, (KT) + 1, 1);                               \
    readA(cu, 1);                                                       \
    mfma_quad(1, 1, bf1);                                               \
    __builtin_amdgcn_s_barrier();                                       \
    asm volatile("" ::: "memory");                                      \
    if (HASNEXT) issueA(nb, (KT) + 1, 1);                               \
    mfma_quad(1, 0, bf0);                                               \
  }

#pragma unroll 1
  for (int kt = 0; kt < 7; ++kt) G2_TILE(kt, "4", "4", "4", 1);
  G2_TILE(7, "4", "2", "0", 0);
#undef G2_TILE

  const int region = cb >> 1;  // 0: s, 1: p, 2: o
  float bv[4]; int cg[4];
#pragma unroll
  for (int n = 0; n < 4; ++n) {
    cg[n] = cb * 256 + (n >> 1) * 128 + wc * 32 + (n & 1) * 16 + rlane;
    bv[n] = bias[cg[n]];
  }

  if (region == 1) {
    float* po = out + (size_t)NBATCH * NOBJ * NH;  // p_vecs region of d_out
#pragma unroll
    for (int m = 0; m < 8; ++m) {
      int rbase = m0 + (m >> 2) * 128 + wr * 64 + (m & 3) * 16 + ((lane >> 4) << 2);
#pragma unroll
      for (int q = 0; q < 4; ++q) {
#pragma unroll
        for (int n = 0; n < 4; ++n) {
          float v = acc[m][n][q] + bv[n];
          v = v > 0.f ? v : 0.f;
          po[(size_t)(rbase + q) * NH + (cg[n] & 511)] = v;
        }
      }
    }
  } else {
    const int sel = region >> 1;          // 0 for s, 1 for o
    const int b = m0 >> 11;               // tile is within one batch
    const int rel = rel_lens[b];
#pragma unroll
    for (int m = 0; m < 8; ++m) {
      int rbase = m0 + (m >> 2) * 128 + wr * 64 + (m & 3) * 16 + ((lane >> 4) << 2);
#pragma unroll
      for (int q = 0; q < 4; ++q) {
        int r = rbase + q;
        if ((r & 2047) < rel) {
          int idx = index[2 * r + sel];
          float* dst = contrib + ((b * NOBJ + idx) << 9);
#pragma unroll
          for (int n = 0; n < 4; ++n) {
            float v = acc[m][n][q] + bv[n];
            v = v > 0.f ? v : 0.f;
            atomicAdd(dst + (cg[n] & 511), v);
          }
        }
      }
    }
  }
}

// pooled[b] = cumsum_b(contrib)
__global__ void k_cumsum(const float* __restrict__ contrib, float* __restrict__ pooled) {
  int i = blockIdx.x * 256 + threadIdx.x;
  if (i >= NOBJ * NH) return;
  float a = 0.f;
#pragma unroll
  for (int b = 0; b < NBATCH; ++b) {
    a += contrib[b * (NOBJ * NH) + i];
    pooled[b * (NOBJ * NH) + i] = a;
  }
}

// new_obj = relu(relu(pooled @ w2a + b2a) @ w2b + b2b), one block per (b,o) row
__global__ void k_mlp2(const float* __restrict__ pooled,
                       const float* __restrict__ w2a, const float* __restrict__ b2a,
                       const float* __restrict__ w2b, const float* __restrict__ b2b,
                       float* __restrict__ out) {
  __shared__ float pr[NH];
  __shared__ float hr[NH];
  int row = blockIdx.x;
  int tid = threadIdx.x;
  pr[tid]       = pooled[(size_t)row * NH + tid];
  pr[tid + 256] = pooled[(size_t)row * NH + tid + 256];
  __syncthreads();
  float s0 = 0.f, s1 = 0.f;
  for (int k = 0; k < NH; ++k) {
    float p = pr[k];
    s0 += p * w2a[k * NH + tid];
    s1 += p * w2a[k * NH + tid + 256];
  }
  s0 += b2a[tid]; s1 += b2a[tid + 256];
  hr[tid]       = s0 > 0.f ? s0 : 0.f;
  hr[tid + 256] = s1 > 0.f ? s1 : 0.f;
  __syncthreads();
  s0 = 0.f; s1 = 0.f;
  for (int k = 0; k < NH; ++k) {
    float h = hr[k];
    s0 += h * w2b[k * NH + tid];
    s1 += h * w2b[k * NH + tid + 256];
  }
  s0 += b2b[tid]; s1 += b2b[tid + 256];
  out[(size_t)row * NH + tid]       = s0 > 0.f ? s0 : 0.f;
  out[(size_t)row * NH + tid + 256] = s1 > 0.f ? s1 : 0.f;
}

extern "C" void kernel_launch(void* const* d_in, const int* in_sizes, int n_in,
                              void* d_out, int out_size, void* d_ws, size_t ws_size,
                              hipStream_t stream) {
  const float* trip     = (const float*)d_in[0];
  const int*   index    = (const int*)d_in[1];
  const int*   rel_lens = (const int*)d_in[2];
  const float* w1a      = (const float*)d_in[3];
  const float* b1a      = (const float*)d_in[4];
  const float* w1b      = (const float*)d_in[5];
  const float* b1b      = (const float*)d_in[6];
  const float* w2a      = (const float*)d_in[7];
  const float* b2a      = (const float*)d_in[8];
  const float* w2b      = (const float*)d_in[9];
  const float* b2b      = (const float*)d_in[10];
  float* out = (float*)d_out;

  char* ws = (char*)d_ws;
  short* wt1a    = (short*)(ws);                          // 512*1536 bf16  (1.50 MB)
  short* wt1b    = (short*)(ws + 1572864);                // 1536*512 bf16  (1.50 MB)
  short* hbuf    = (short*)(ws + 3145728);                // 65536*512 bf16 (64 MB), chunked
  float* contrib = (float*)(ws + 70254592);               // 32*18*512 f32
  float* pooled  = contrib + NBATCH * NOBJ * NH;

  k_prep<<<3072, 256, 0, stream>>>(w1a, wt1a, KIN, NH, 24, NH * 1536);
  k_prep<<<3072, 256, 0, stream>>>(w1b, wt1b, NH, NTOT, 8, NTOT * NH);
  hipMemsetAsync(contrib, 0, (size_t)NBATCH * NOBJ * NH * sizeof(float), stream);
  k_gemm1<<<512, 512, 0, stream>>>(trip, wt1a, b1a, hbuf);
  k_gemm2<<<1536, 512, 0, stream>>>(hbuf, wt1b, b1b, index, rel_lens, contrib, out);
  k_cumsum<<<36, 256, 0, stream>>>(contrib, pooled);
  k_mlp2<<<576, 256, 0, stream>>>(pooled, w2a, b2a, w2b, b2b, out);
}